// Round 1
// baseline (322.541 us; speedup 1.0000x reference)
//
#include <hip/hip_runtime.h>

#define NB     8192
#define LATENT 32
#define HDIM   64
#define SEQ    180
#define KIN    96     // LATENT + HDIM

typedef __bf16 bf16x8 __attribute__((ext_vector_type(8)));
typedef float  f32x4  __attribute__((ext_vector_type(4)));

#define L2E 1.44269504088896340736f

__device__ __forceinline__ float sigm_f(float x) {
    float e = __builtin_amdgcn_exp2f(-L2E * x);
    return __builtin_amdgcn_rcpf(1.0f + e);
}
__device__ __forceinline__ float tanh_f(float x) {
    float e = __builtin_amdgcn_exp2f((2.0f * L2E) * x);
    return 1.0f - 2.0f * __builtin_amdgcn_rcpf(1.0f + e);
}

// ---------------- kernel 1: h0 = tanh(fc([z, embed(labels)])) ----------------
// One thread per batch element; j-loop uniform -> fc_w reads become s_loads.
__global__ void h0_kernel(const float* __restrict__ z,
                          const int* __restrict__ labels,
                          const float* __restrict__ embed_w,
                          const float* __restrict__ fc_w,
                          const float* __restrict__ fc_b,
                          float* __restrict__ h0out) {
    int b = blockIdx.x * blockDim.x + threadIdx.x;
    float x[KIN];
    const float* zp = z + b * LATENT;
#pragma unroll
    for (int k = 0; k < LATENT / 4; ++k) {
        f32x4 v = *(const f32x4*)(zp + 4 * k);
        x[4 * k + 0] = v[0]; x[4 * k + 1] = v[1];
        x[4 * k + 2] = v[2]; x[4 * k + 3] = v[3];
    }
    const float* ep = embed_w + labels[b] * HDIM;
#pragma unroll
    for (int k = 0; k < HDIM / 4; ++k) {
        f32x4 v = *(const f32x4*)(ep + 4 * k);
        x[LATENT + 4 * k + 0] = v[0]; x[LATENT + 4 * k + 1] = v[1];
        x[LATENT + 4 * k + 2] = v[2]; x[LATENT + 4 * k + 3] = v[3];
    }
    float* op = h0out + b * HDIM;
    for (int j = 0; j < HDIM; ++j) {       // j uniform across the wave
        const float* wr = fc_w + j * KIN;  // -> scalar loads
        float a0 = fc_b[j], a1 = 0.f, a2 = 0.f, a3 = 0.f;
#pragma unroll
        for (int k = 0; k < KIN; k += 4) {
            a0 += wr[k + 0] * x[k + 0];
            a1 += wr[k + 1] * x[k + 1];
            a2 += wr[k + 2] * x[k + 2];
            a3 += wr[k + 3] * x[k + 3];
        }
        op[j] = tanh_f((a0 + a1) + (a2 + a3));
    }
}

// ---------------- kernel 2: 180 GRU steps + output head ----------------
// Block = 256 threads = 4 waves, 16 batch rows per block, 512 blocks.
// Wave w owns gate columns j in [16w, 16w+16) for all three gates.
// h kept in LDS: fp32 plane (exact state) + bf16 hi/lo planes (A-fragments).
#define MT  16
#define S32 68   // fp32 plane row stride (floats)   -> conflict-free-ish
#define SB  72   // bf16 plane row stride (elements) -> 16B-aligned rows

__global__ __launch_bounds__(256) void gru_kernel(
        const float* __restrict__ h0, const float* __restrict__ w_hh,
        const float* __restrict__ b_ih, const float* __restrict__ b_hh,
        const float* __restrict__ out_w, const float* __restrict__ out_b,
        float* __restrict__ out) {
    __shared__ float  h32[MT * S32];
    __shared__ __bf16 hhi[MT * SB];
    __shared__ __bf16 hlo[MT * SB];

    const int t = threadIdx.x;
    const int w = t >> 6;          // wave 0..3
    const int l = t & 63;
    const int q = l >> 4;          // quad 0..3
    const int n16 = l & 15;
    const int bbase = blockIdx.x * MT;

    // ---- stage h0 tile into all three LDS planes ----
    {
        int idx = t * 4;           // 0..1023 over [16][64]
        int m = idx >> 6;
        int c = idx & 63;
        f32x4 v = *(const f32x4*)(h0 + (bbase + m) * HDIM + c);
#pragma unroll
        for (int i2 = 0; i2 < 4; ++i2) {
            float f = v[i2];
            __bf16 hi = (__bf16)f;
            h32[m * S32 + c + i2] = f;
            hhi[m * SB + c + i2] = hi;
            hlo[m * SB + c + i2] = (__bf16)(f - (float)hi);
        }
    }

    // ---- persistent weight fragments (hi/lo split), 48 VGPRs ----
    // B-frag layout for mfma_f32_16x16x32_bf16: B[k = q*8+j][n = lane&15]
    // value = w_hh[n_global][k], n_global = g*64 + 16w + n16
    bf16x8 whi[3][2], wlo[3][2];
    const int jg = 16 * w + n16;
#pragma unroll
    for (int g = 0; g < 3; ++g) {
        const float* pr = w_hh + (g * 64 + jg) * HDIM;
#pragma unroll
        for (int ks = 0; ks < 2; ++ks) {
            const float* p = pr + ks * 32 + q * 8;
            f32x4 va = *(const f32x4*)(p);
            f32x4 vb = *(const f32x4*)(p + 4);
#pragma unroll
            for (int j2 = 0; j2 < 4; ++j2) {
                __bf16 hiA = (__bf16)va[j2];
                whi[g][ks][j2] = hiA;
                wlo[g][ks][j2] = (__bf16)(va[j2] - (float)hiA);
                __bf16 hiB = (__bf16)vb[j2];
                whi[g][ks][4 + j2] = hiB;
                wlo[g][ks][4 + j2] = (__bf16)(vb[j2] - (float)hiB);
            }
        }
    }

    // biases (torch GRU): r,z get b_ih+b_hh up front; n keeps b_hh inside the
    // r-multiplied term and adds b_ih after.
    const float brz0  = b_ih[jg] + b_hh[jg];
    const float brz1  = b_ih[64 + jg] + b_hh[64 + jg];
    const float bnacc = b_hh[128 + jg];
    const float bnin  = b_ih[128 + jg];

    // output head weights, per-lane k-chunk (k = n16*4 .. +3)
    const f32x4 wo0 = *(const f32x4*)(out_w + n16 * 4);
    const f32x4 wo1 = *(const f32x4*)(out_w + HDIM + n16 * 4);
    const float ob0 = out_b[0], ob1 = out_b[1];
    const int mo = 4 * w + q;                       // batch row this lane-group reduces
    float* outp = out + (size_t)(bbase + mo) * SEQ * 2;

    __syncthreads();

    // out-dot: dot(h32[mo], out_w[o]) via per-lane dot4 + 16-lane butterfly
    auto out_row = [&](int row) {
        f32x4 hv = *(const f32x4*)(h32 + mo * S32 + n16 * 4);
        float p0 = hv[0] * wo0[0] + hv[1] * wo0[1] + hv[2] * wo0[2] + hv[3] * wo0[3];
        float p1 = hv[0] * wo1[0] + hv[1] * wo1[1] + hv[2] * wo1[2] + hv[3] * wo1[3];
#pragma unroll
        for (int msk = 1; msk < 16; msk <<= 1) {
            p0 += __shfl_xor(p0, msk);
            p1 += __shfl_xor(p1, msk);
        }
        if (n16 == 0) {
            float2 o2 = make_float2(p0 + ob0, p1 + ob1);
            *(float2*)(outp + row * 2) = o2;
        }
    };

    for (int i = 0; i < SEQ; ++i) {
        // h32/hhi/hlo currently hold state after i steps (= hs[i-1] for i>=1)
        if (i > 0) out_row(i - 1);

        // A-fragments: A[m = n16][k = q*8+j], k-halves ks=0/1
        bf16x8 ahi0 = *(bf16x8*)(hhi + n16 * SB + q * 8);
        bf16x8 ahi1 = *(bf16x8*)(hhi + n16 * SB + 32 + q * 8);
        bf16x8 alo0 = *(bf16x8*)(hlo + n16 * SB + q * 8);
        bf16x8 alo1 = *(bf16x8*)(hlo + n16 * SB + 32 + q * 8);
        float hold[4];
#pragma unroll
        for (int r = 0; r < 4; ++r) hold[r] = h32[(q * 4 + r) * S32 + jg];

        __syncthreads();   // all reads of state i done before overwrite

        f32x4 accR = {brz0, brz0, brz0, brz0};
        f32x4 accZ = {brz1, brz1, brz1, brz1};
        f32x4 accN = {bnacc, bnacc, bnacc, bnacc};

        // gh = h*W^T with bf16 hi/lo split: hi*hi + hi*lo + lo*hi (~fp32 acc)
        accR = __builtin_amdgcn_mfma_f32_16x16x32_bf16(ahi0, whi[0][0], accR, 0, 0, 0);
        accR = __builtin_amdgcn_mfma_f32_16x16x32_bf16(ahi0, wlo[0][0], accR, 0, 0, 0);
        accR = __builtin_amdgcn_mfma_f32_16x16x32_bf16(alo0, whi[0][0], accR, 0, 0, 0);
        accR = __builtin_amdgcn_mfma_f32_16x16x32_bf16(ahi1, whi[0][1], accR, 0, 0, 0);
        accR = __builtin_amdgcn_mfma_f32_16x16x32_bf16(ahi1, wlo[0][1], accR, 0, 0, 0);
        accR = __builtin_amdgcn_mfma_f32_16x16x32_bf16(alo1, whi[0][1], accR, 0, 0, 0);

        accZ = __builtin_amdgcn_mfma_f32_16x16x32_bf16(ahi0, whi[1][0], accZ, 0, 0, 0);
        accZ = __builtin_amdgcn_mfma_f32_16x16x32_bf16(ahi0, wlo[1][0], accZ, 0, 0, 0);
        accZ = __builtin_amdgcn_mfma_f32_16x16x32_bf16(alo0, whi[1][0], accZ, 0, 0, 0);
        accZ = __builtin_amdgcn_mfma_f32_16x16x32_bf16(ahi1, whi[1][1], accZ, 0, 0, 0);
        accZ = __builtin_amdgcn_mfma_f32_16x16x32_bf16(ahi1, wlo[1][1], accZ, 0, 0, 0);
        accZ = __builtin_amdgcn_mfma_f32_16x16x32_bf16(alo1, whi[1][1], accZ, 0, 0, 0);

        accN = __builtin_amdgcn_mfma_f32_16x16x32_bf16(ahi0, whi[2][0], accN, 0, 0, 0);
        accN = __builtin_amdgcn_mfma_f32_16x16x32_bf16(ahi0, wlo[2][0], accN, 0, 0, 0);
        accN = __builtin_amdgcn_mfma_f32_16x16x32_bf16(alo0, whi[2][0], accN, 0, 0, 0);
        accN = __builtin_amdgcn_mfma_f32_16x16x32_bf16(ahi1, whi[2][1], accN, 0, 0, 0);
        accN = __builtin_amdgcn_mfma_f32_16x16x32_bf16(ahi1, wlo[2][1], accN, 0, 0, 0);
        accN = __builtin_amdgcn_mfma_f32_16x16x32_bf16(alo1, whi[2][1], accN, 0, 0, 0);

        // gates + state update; C/D layout: m = q*4+reg, n(col j) = n16
#pragma unroll
        for (int r = 0; r < 4; ++r) {
            float rg = sigm_f(accR[r]);
            float zg = sigm_f(accZ[r]);
            float ng = tanh_f(bnin + rg * accN[r]);
            float hn = ng + zg * (hold[r] - ng);
            int m = q * 4 + r;
            h32[m * S32 + jg] = hn;
            __bf16 hi = (__bf16)hn;
            hhi[m * SB + jg] = hi;
            hlo[m * SB + jg] = (__bf16)(hn - (float)hi);
        }
        __syncthreads();   // state i+1 published
    }

    out_row(SEQ - 1);      // final state hs[179]
}

extern "C" void kernel_launch(void* const* d_in, const int* in_sizes, int n_in,
                              void* d_out, int out_size, void* d_ws, size_t ws_size,
                              hipStream_t stream) {
    (void)in_sizes; (void)n_in; (void)out_size; (void)ws_size;
    const float* z       = (const float*)d_in[0];
    const int*   labels  = (const int*)d_in[1];
    const float* embed_w = (const float*)d_in[2];
    const float* fc_w    = (const float*)d_in[3];
    const float* fc_b    = (const float*)d_in[4];
    // d_in[5] = w_ih: unused (GRU input is all zeros; b_ih carries the effect)
    const float* w_hh    = (const float*)d_in[6];
    const float* b_ih    = (const float*)d_in[7];
    const float* b_hh    = (const float*)d_in[8];
    const float* out_w   = (const float*)d_in[9];
    const float* out_b   = (const float*)d_in[10];
    float* out = (float*)d_out;
    float* h0ws = (float*)d_ws;   // 8192*64 fp32 = 2 MB

    h0_kernel<<<NB / 64, 64, 0, stream>>>(z, labels, embed_w, fc_w, fc_b, h0ws);
    gru_kernel<<<NB / MT, 256, 0, stream>>>(h0ws, w_hh, b_ih, b_hh, out_w, out_b, out);
}

// Round 2
// 232.493 us; speedup vs baseline: 1.3873x; 1.3873x over previous
//
#include <hip/hip_runtime.h>

#define NB     8192
#define HDIM   64
#define SEQ    180
#define MT     16     // batch rows per block
#define SB     72     // bf16 LDS plane row stride (elements, 144 B = 9*16B)
#define XSP    100    // xs prologue row stride (floats)

typedef __bf16 bf16x8 __attribute__((ext_vector_type(8)));
typedef float  f32x4  __attribute__((ext_vector_type(4)));

#define L2E 1.44269504088896340736f

__device__ __forceinline__ float sigm_f(float x) {
    float e = __builtin_amdgcn_exp2f(-L2E * x);
    return __builtin_amdgcn_rcpf(1.0f + e);
}
__device__ __forceinline__ float tanh_f(float x) {
    float e = __builtin_amdgcn_exp2f((2.0f * L2E) * x);
    return 1.0f - 2.0f * __builtin_amdgcn_rcpf(1.0f + e);
}

// One fused kernel: h0 prologue + 180 GRU steps + per-step output head.
// Block = 256 threads = 4 waves, 16 batch rows, 512 blocks (2 blocks/CU).
// Wave w owns gate columns jg = 16w + n16 for all three gates.
// State: fp32 exact in registers (hprev, C-layout); bf16 hi/lo planes in LDS
// (double-buffered -> single barrier per step) feed the MFMA A-operands.
__global__ __launch_bounds__(256) void gru_all(
        const float* __restrict__ z, const int* __restrict__ labels,
        const float* __restrict__ embed_w, const float* __restrict__ fc_w,
        const float* __restrict__ fc_b, const float* __restrict__ w_hh,
        const float* __restrict__ b_ih, const float* __restrict__ b_hh,
        const float* __restrict__ out_w, const float* __restrict__ out_b,
        float* __restrict__ out) {
    __shared__ __align__(16) __bf16 hbuf[2][2][MT * SB];  // [buf][hi/lo]
    __shared__ __align__(16) float  xs[MT * XSP];         // h0 input [z|embed]

    const int t = threadIdx.x;
    const int w = t >> 6;          // wave 0..3
    const int l = t & 63;
    const int q = l >> 4;          // quad 0..3
    const int n16 = l & 15;
    const int jg = 16 * w + n16;   // gate column this lane owns
    const int bbase = blockIdx.x * MT;

    // ---- prologue A: stage x = [z, embed(labels)] for 16 rows into LDS ----
    for (int c = t; c < MT * 24; c += 256) {    // 24 f32x4 chunks per row
        int m = c / 24, kk = (c % 24) * 4;
        f32x4 v;
        if (kk < 32) v = *(const f32x4*)(z + (size_t)(bbase + m) * 32 + kk);
        else         v = *(const f32x4*)(embed_w + labels[bbase + m] * 64 + (kk - 32));
        *(f32x4*)(xs + m * XSP + kk) = v;
    }

    // ---- persistent w_hh fragments (hi/lo split), 48 VGPRs ----
    // B-frag for mfma_f32_16x16x32_bf16: B[k = q*8+j][n16]; value w_hh[jg_g][k]
    bf16x8 whi[3][2], wlo[3][2];
#pragma unroll
    for (int g = 0; g < 3; ++g) {
        const float* pr = w_hh + (g * 64 + jg) * HDIM;
#pragma unroll
        for (int ks = 0; ks < 2; ++ks) {
            const float* p = pr + ks * 32 + q * 8;
            f32x4 va = *(const f32x4*)(p);
            f32x4 vb = *(const f32x4*)(p + 4);
#pragma unroll
            for (int j2 = 0; j2 < 4; ++j2) {
                __bf16 hiA = (__bf16)va[j2];
                whi[g][ks][j2] = hiA;
                wlo[g][ks][j2] = (__bf16)(va[j2] - (float)hiA);
                __bf16 hiB = (__bf16)vb[j2];
                whi[g][ks][4 + j2] = hiB;
                wlo[g][ks][4 + j2] = (__bf16)(vb[j2] - (float)hiB);
            }
        }
    }

    // ---- output-head B fragments: B[k][n] = out_w[n][k] for n<2 else 0 ----
    bf16x8 obhi[2], oblo[2];
#pragma unroll
    for (int ks = 0; ks < 2; ++ks) {
        f32x4 va = {0.f, 0.f, 0.f, 0.f}, vb = {0.f, 0.f, 0.f, 0.f};
        if (n16 < 2) {
            va = *(const f32x4*)(out_w + n16 * 64 + ks * 32 + q * 8);
            vb = *(const f32x4*)(out_w + n16 * 64 + ks * 32 + q * 8 + 4);
        }
#pragma unroll
        for (int j2 = 0; j2 < 4; ++j2) {
            __bf16 hiA = (__bf16)va[j2];
            obhi[ks][j2] = hiA;
            oblo[ks][j2] = (__bf16)(va[j2] - (float)hiA);
            __bf16 hiB = (__bf16)vb[j2];
            obhi[ks][4 + j2] = hiB;
            oblo[ks][4 + j2] = (__bf16)(vb[j2] - (float)hiB);
        }
    }
    const float bo = (n16 == 0) ? out_b[0] : (n16 == 1) ? out_b[1] : 0.f;
    const f32x4 obias = {bo, bo, bo, bo};

    // biases (torch GRU): r,z fold b_ih+b_hh; n keeps b_hh inside r*(.), b_ih after
    const float brz0  = b_ih[jg] + b_hh[jg];
    const float brz1  = b_ih[64 + jg] + b_hh[64 + jg];
    const float bnacc = b_hh[128 + jg];
    const float bnin  = b_ih[128 + jg];

    __syncthreads();   // xs ready

    // ---- prologue B: h0 = tanh(fc_b + fc_w . x); each lane -> its 4 holds ----
    float hprev[4];
    {
        float a[4];
#pragma unroll
        for (int r = 0; r < 4; ++r) a[r] = fc_b[jg];
        const float* wr = fc_w + jg * 96;
        for (int kc = 0; kc < 24; ++kc) {
            f32x4 wv = *(const f32x4*)(wr + kc * 4);
#pragma unroll
            for (int r = 0; r < 4; ++r) {
                f32x4 xv = *(const f32x4*)(xs + (4 * q + r) * XSP + kc * 4);
                a[r] += wv[0] * xv[0] + wv[1] * xv[1] + wv[2] * xv[2] + wv[3] * xv[3];
            }
        }
#pragma unroll
        for (int r = 0; r < 4; ++r) {
            float h = tanh_f(a[r]);
            hprev[r] = h;
            __bf16 hi = (__bf16)h;
            hbuf[0][0][(4 * q + r) * SB + jg] = hi;
            hbuf[0][1][(4 * q + r) * SB + jg] = (__bf16)(h - (float)hi);
        }
    }
    __syncthreads();   // state 0 published in buf 0

    for (int i = 0; i < SEQ; ++i) {
        const int p = i & 1;
        const __bf16* Hh = hbuf[p][0];
        const __bf16* Hl = hbuf[p][1];
        // A-frags of state i (= hs[i-1]): A[m=n16][k=q*8+j], k-halves
        bf16x8 ahi0 = *(const bf16x8*)(Hh + n16 * SB + q * 8);
        bf16x8 ahi1 = *(const bf16x8*)(Hh + n16 * SB + 32 + q * 8);
        bf16x8 alo0 = *(const bf16x8*)(Hl + n16 * SB + q * 8);
        bf16x8 alo1 = *(const bf16x8*)(Hl + n16 * SB + 32 + q * 8);

        // output row i-1 on duty wave (round-robin): D[m][n<2] = hs[i-1].out_w^T
        if (i > 0 && w == ((i - 1) & 3)) {
            f32x4 o = obias;
            o = __builtin_amdgcn_mfma_f32_16x16x32_bf16(ahi0, obhi[0], o, 0, 0, 0);
            o = __builtin_amdgcn_mfma_f32_16x16x32_bf16(ahi1, obhi[1], o, 0, 0, 0);
            o = __builtin_amdgcn_mfma_f32_16x16x32_bf16(alo0, obhi[0], o, 0, 0, 0);
            o = __builtin_amdgcn_mfma_f32_16x16x32_bf16(alo1, obhi[1], o, 0, 0, 0);
            o = __builtin_amdgcn_mfma_f32_16x16x32_bf16(ahi0, oblo[0], o, 0, 0, 0);
            o = __builtin_amdgcn_mfma_f32_16x16x32_bf16(ahi1, oblo[1], o, 0, 0, 0);
            if (n16 < 2) {
#pragma unroll
                for (int r = 0; r < 4; ++r)
                    out[(size_t)(bbase + 4 * q + r) * (SEQ * 2) + (i - 1) * 2 + n16] = o[r];
            }
        }

        f32x4 accR = {brz0, brz0, brz0, brz0};
        f32x4 accZ = {brz1, brz1, brz1, brz1};
        f32x4 accN = {bnacc, bnacc, bnacc, bnacc};

        accR = __builtin_amdgcn_mfma_f32_16x16x32_bf16(ahi0, whi[0][0], accR, 0, 0, 0);
        accR = __builtin_amdgcn_mfma_f32_16x16x32_bf16(ahi0, wlo[0][0], accR, 0, 0, 0);
        accR = __builtin_amdgcn_mfma_f32_16x16x32_bf16(alo0, whi[0][0], accR, 0, 0, 0);
        accR = __builtin_amdgcn_mfma_f32_16x16x32_bf16(ahi1, whi[0][1], accR, 0, 0, 0);
        accR = __builtin_amdgcn_mfma_f32_16x16x32_bf16(ahi1, wlo[0][1], accR, 0, 0, 0);
        accR = __builtin_amdgcn_mfma_f32_16x16x32_bf16(alo1, whi[0][1], accR, 0, 0, 0);

        accZ = __builtin_amdgcn_mfma_f32_16x16x32_bf16(ahi0, whi[1][0], accZ, 0, 0, 0);
        accZ = __builtin_amdgcn_mfma_f32_16x16x32_bf16(ahi0, wlo[1][0], accZ, 0, 0, 0);
        accZ = __builtin_amdgcn_mfma_f32_16x16x32_bf16(alo0, whi[1][0], accZ, 0, 0, 0);
        accZ = __builtin_amdgcn_mfma_f32_16x16x32_bf16(ahi1, whi[1][1], accZ, 0, 0, 0);
        accZ = __builtin_amdgcn_mfma_f32_16x16x32_bf16(ahi1, wlo[1][1], accZ, 0, 0, 0);
        accZ = __builtin_amdgcn_mfma_f32_16x16x32_bf16(alo1, whi[1][1], accZ, 0, 0, 0);

        accN = __builtin_amdgcn_mfma_f32_16x16x32_bf16(ahi0, whi[2][0], accN, 0, 0, 0);
        accN = __builtin_amdgcn_mfma_f32_16x16x32_bf16(ahi0, wlo[2][0], accN, 0, 0, 0);
        accN = __builtin_amdgcn_mfma_f32_16x16x32_bf16(alo0, whi[2][0], accN, 0, 0, 0);
        accN = __builtin_amdgcn_mfma_f32_16x16x32_bf16(ahi1, whi[2][1], accN, 0, 0, 0);
        accN = __builtin_amdgcn_mfma_f32_16x16x32_bf16(ahi1, wlo[2][1], accN, 0, 0, 0);
        accN = __builtin_amdgcn_mfma_f32_16x16x32_bf16(alo1, whi[2][1], accN, 0, 0, 0);

        __bf16* Nh = hbuf[1 - p][0];
        __bf16* Nl = hbuf[1 - p][1];
#pragma unroll
        for (int r = 0; r < 4; ++r) {
            float rg = sigm_f(accR[r]);
            float zg = sigm_f(accZ[r]);
            float ng = tanh_f(bnin + rg * accN[r]);
            float hn = ng + zg * (hprev[r] - ng);
            hprev[r] = hn;
            __bf16 hi = (__bf16)hn;
            Nh[(4 * q + r) * SB + jg] = hi;
            Nl[(4 * q + r) * SB + jg] = (__bf16)(hn - (float)hi);
        }
        __syncthreads();   // state i+1 published in buf 1-p
    }

    // final output row SEQ-1 from state SEQ (in buf[SEQ&1] = buf 0)
    if (w == ((SEQ - 1) & 3)) {
        const __bf16* Hh = hbuf[0][0];
        const __bf16* Hl = hbuf[0][1];
        bf16x8 ahi0 = *(const bf16x8*)(Hh + n16 * SB + q * 8);
        bf16x8 ahi1 = *(const bf16x8*)(Hh + n16 * SB + 32 + q * 8);
        bf16x8 alo0 = *(const bf16x8*)(Hl + n16 * SB + q * 8);
        bf16x8 alo1 = *(const bf16x8*)(Hl + n16 * SB + 32 + q * 8);
        f32x4 o = obias;
        o = __builtin_amdgcn_mfma_f32_16x16x32_bf16(ahi0, obhi[0], o, 0, 0, 0);
        o = __builtin_amdgcn_mfma_f32_16x16x32_bf16(ahi1, obhi[1], o, 0, 0, 0);
        o = __builtin_amdgcn_mfma_f32_16x16x32_bf16(alo0, obhi[0], o, 0, 0, 0);
        o = __builtin_amdgcn_mfma_f32_16x16x32_bf16(alo1, obhi[1], o, 0, 0, 0);
        o = __builtin_amdgcn_mfma_f32_16x16x32_bf16(ahi0, oblo[0], o, 0, 0, 0);
        o = __builtin_amdgcn_mfma_f32_16x16x32_bf16(ahi1, oblo[1], o, 0, 0, 0);
        if (n16 < 2) {
#pragma unroll
            for (int r = 0; r < 4; ++r)
                out[(size_t)(bbase + 4 * q + r) * (SEQ * 2) + (SEQ - 1) * 2 + n16] = o[r];
        }
    }
}

extern "C" void kernel_launch(void* const* d_in, const int* in_sizes, int n_in,
                              void* d_out, int out_size, void* d_ws, size_t ws_size,
                              hipStream_t stream) {
    (void)in_sizes; (void)n_in; (void)out_size; (void)d_ws; (void)ws_size;
    const float* z       = (const float*)d_in[0];
    const int*   labels  = (const int*)d_in[1];
    const float* embed_w = (const float*)d_in[2];
    const float* fc_w    = (const float*)d_in[3];
    const float* fc_b    = (const float*)d_in[4];
    // d_in[5] = w_ih: unused (GRU input is all zeros; b_ih carries the effect)
    const float* w_hh    = (const float*)d_in[6];
    const float* b_ih    = (const float*)d_in[7];
    const float* b_hh    = (const float*)d_in[8];
    const float* out_w   = (const float*)d_in[9];
    const float* out_b   = (const float*)d_in[10];
    float* out = (float*)d_out;

    gru_all<<<NB / MT, 256, 0, stream>>>(z, labels, embed_w, fc_w, fc_b,
                                         w_hh, b_ih, b_hh, out_w, out_b, out);
}

// Round 3
// 229.871 us; speedup vs baseline: 1.4031x; 1.0114x over previous
//
#include <hip/hip_runtime.h>

#define NB     8192
#define HDIM   64
#define SEQ    180
#define MT     16     // batch rows per block
#define SB     72     // bf16 LDS plane row stride (elements, 144 B)
#define XSP    100    // xs prologue row stride (floats)

typedef __bf16 bf16x8 __attribute__((ext_vector_type(8)));
typedef float  f32x4  __attribute__((ext_vector_type(4)));

#define L2E 1.44269504088896340736f

__device__ __forceinline__ float tanh_f(float x) {
    float e = __builtin_amdgcn_exp2f((2.0f * L2E) * x);
    return 1.0f - 2.0f * __builtin_amdgcn_rcpf(1.0f + e);
}

#define MFMA __builtin_amdgcn_mfma_f32_16x16x32_bf16

// One fused kernel: h0 prologue + 180 GRU steps + per-step output head.
// Block = 256 threads = 4 waves, 16 batch rows, 512 blocks (2 blocks/CU).
// Wave w owns gate columns jg = 16w + n16 for all three gates.
// fp32 state in registers (hprev); bf16 hi/lo planes in LDS (double-buffered,
// 1 barrier/step) feed MFMA A-operands. Time loop unrolled x4 so buffer
// parity, duty wave, and all LDS/global addresses are static.
__global__ __launch_bounds__(256) void gru_all(
        const float* __restrict__ z, const int* __restrict__ labels,
        const float* __restrict__ embed_w, const float* __restrict__ fc_w,
        const float* __restrict__ fc_b, const float* __restrict__ w_hh,
        const float* __restrict__ b_ih, const float* __restrict__ b_hh,
        const float* __restrict__ out_w, const float* __restrict__ out_b,
        float* __restrict__ out) {
    __shared__ __align__(16) __bf16 hbuf[2][2][MT * SB];  // [buf][hi/lo]
    __shared__ __align__(16) float  xs[MT * XSP];         // h0 input [z|embed]

    const int t = threadIdx.x;
    const int w = t >> 6;          // wave 0..3
    const int l = t & 63;
    const int q = l >> 4;          // quad 0..3
    const int n16 = l & 15;
    const int jg = 16 * w + n16;   // gate column this lane owns
    const int bbase = blockIdx.x * MT;

    // ---- prologue A: stage x = [z, embed(labels)] for 16 rows into LDS ----
    for (int c = t; c < MT * 24; c += 256) {    // 24 f32x4 chunks per row
        int m = c / 24, kk = (c % 24) * 4;
        f32x4 v;
        if (kk < 32) v = *(const f32x4*)(z + (size_t)(bbase + m) * 32 + kk);
        else         v = *(const f32x4*)(embed_w + labels[bbase + m] * 64 + (kk - 32));
        *(f32x4*)(xs + m * XSP + kk) = v;
    }

    // ---- persistent w_hh fragments (hi/lo split), 48 VGPRs ----
    // B-frag for mfma_f32_16x16x32_bf16: B[k = q*8+j][n16]; value w_hh[jg_g][k]
    bf16x8 whi[3][2], wlo[3][2];
#pragma unroll
    for (int g = 0; g < 3; ++g) {
        const float* pr = w_hh + (g * 64 + jg) * HDIM;
#pragma unroll
        for (int ks = 0; ks < 2; ++ks) {
            const float* p = pr + ks * 32 + q * 8;
            f32x4 va = *(const f32x4*)(p);
            f32x4 vb = *(const f32x4*)(p + 4);
#pragma unroll
            for (int j2 = 0; j2 < 4; ++j2) {
                __bf16 hiA = (__bf16)va[j2];
                whi[g][ks][j2] = hiA;
                wlo[g][ks][j2] = (__bf16)(va[j2] - (float)hiA);
                __bf16 hiB = (__bf16)vb[j2];
                whi[g][ks][4 + j2] = hiB;
                wlo[g][ks][4 + j2] = (__bf16)(vb[j2] - (float)hiB);
            }
        }
    }

    // ---- output-head B fragments: B[k][n] = out_w[n][k] for n<2 else 0 ----
    bf16x8 obhi[2], oblo[2];
#pragma unroll
    for (int ks = 0; ks < 2; ++ks) {
        f32x4 va = {0.f, 0.f, 0.f, 0.f}, vb = {0.f, 0.f, 0.f, 0.f};
        if (n16 < 2) {
            va = *(const f32x4*)(out_w + n16 * 64 + ks * 32 + q * 8);
            vb = *(const f32x4*)(out_w + n16 * 64 + ks * 32 + q * 8 + 4);
        }
#pragma unroll
        for (int j2 = 0; j2 < 4; ++j2) {
            __bf16 hiA = (__bf16)va[j2];
            obhi[ks][j2] = hiA;
            oblo[ks][j2] = (__bf16)(va[j2] - (float)hiA);
            __bf16 hiB = (__bf16)vb[j2];
            obhi[ks][4 + j2] = hiB;
            oblo[ks][4 + j2] = (__bf16)(vb[j2] - (float)hiB);
        }
    }
    const float bo = (n16 == 0) ? out_b[0] : (n16 == 1) ? out_b[1] : 0.f;
    const f32x4 obias = {bo, bo, bo, bo};
    const f32x4 kZ = {0.f, 0.f, 0.f, 0.f};   // persistent zero C-operand

    // per-lane gate constants (biases folded into the exp2 fma)
    const float cR    = -L2E * (b_ih[jg] + b_hh[jg]);
    const float cZ    = -L2E * (b_ih[64 + jg] + b_hh[64 + jg]);
    const float bnacc = b_hh[128 + jg];
    const float cN    = 2.0f * L2E * b_ih[128 + jg];

    const int rdoff = n16 * SB + q * 8;    // A-frag element offset
    const int wroff = (4 * q) * SB + jg;   // state-write element offset
    float* oph = out + (size_t)(bbase + 4 * q) * (SEQ * 2) + n16;

    __syncthreads();   // xs ready

    // ---- prologue B: h0 = tanh(fc_b + fc_w . x); each lane -> its 4 rows ----
    float hprev[4];
    {
        float a[4];
#pragma unroll
        for (int r = 0; r < 4; ++r) a[r] = fc_b[jg];
        const float* wr = fc_w + jg * 96;
        for (int kc = 0; kc < 24; ++kc) {
            f32x4 wv = *(const f32x4*)(wr + kc * 4);
#pragma unroll
            for (int r = 0; r < 4; ++r) {
                f32x4 xv = *(const f32x4*)(xs + (4 * q + r) * XSP + kc * 4);
                a[r] += wv[0] * xv[0] + wv[1] * xv[1] + wv[2] * xv[2] + wv[3] * xv[3];
            }
        }
#pragma unroll
        for (int r = 0; r < 4; ++r) {
            float h = tanh_f(a[r]);
            hprev[r] = h;
            __bf16 hb = (__bf16)h;
            hbuf[0][0][wroff + r * SB] = hb;
            hbuf[0][1][wroff + r * SB] = (__bf16)(h - (float)hb);
        }
    }
    __syncthreads();   // state 0 published in buf 0

    for (int u = 0; u < SEQ / 4; ++u) {
#pragma unroll
        for (int s = 0; s < 4; ++s) {
            const int p = s & 1;
            const __bf16* Hh = hbuf[p][0];
            const __bf16* Hl = hbuf[p][1];
            __bf16* Nh = hbuf[1 - p][0];
            __bf16* Nl = hbuf[1 - p][1];

            // A-frags of state i = 4u+s: A[m=n16][k=q*8+j], two k-halves
            bf16x8 ahi0 = *(const bf16x8*)(Hh + rdoff);
            bf16x8 ahi1 = *(const bf16x8*)(Hh + rdoff + 32);
            bf16x8 alo0 = *(const bf16x8*)(Hl + rdoff);
            bf16x8 alo1 = *(const bf16x8*)(Hl + rdoff + 32);

            // output row i-1 (state i) on static duty wave (s+3)&3
            if ((u | s) != 0 && w == ((s + 3) & 3)) {
                f32x4 o = obias;
                o = MFMA(ahi0, obhi[0], o, 0, 0, 0);
                o = MFMA(ahi1, obhi[1], o, 0, 0, 0);
                o = MFMA(alo0, obhi[0], o, 0, 0, 0);
                o = MFMA(alo1, obhi[1], o, 0, 0, 0);
                o = MFMA(ahi0, oblo[0], o, 0, 0, 0);
                o = MFMA(ahi1, oblo[1], o, 0, 0, 0);
                if (n16 < 2) {
#pragma unroll
                    for (int r = 0; r < 4; ++r)
                        oph[r * (SEQ * 2) + 2 * s - 2] = o[r];
                }
            }

            f32x4 aR, aZ, aN;
            aR = MFMA(ahi0, whi[0][0], kZ, 0, 0, 0);
            aZ = MFMA(ahi0, whi[1][0], kZ, 0, 0, 0);
            aN = MFMA(ahi0, whi[2][0], kZ, 0, 0, 0);
            aR = MFMA(alo0, whi[0][0], aR, 0, 0, 0);
            aZ = MFMA(alo0, whi[1][0], aZ, 0, 0, 0);
            aN = MFMA(alo0, whi[2][0], aN, 0, 0, 0);
            aR = MFMA(ahi0, wlo[0][0], aR, 0, 0, 0);
            aZ = MFMA(ahi0, wlo[1][0], aZ, 0, 0, 0);
            aN = MFMA(ahi0, wlo[2][0], aN, 0, 0, 0);
            aR = MFMA(ahi1, whi[0][1], aR, 0, 0, 0);
            aZ = MFMA(ahi1, whi[1][1], aZ, 0, 0, 0);
            aN = MFMA(ahi1, whi[2][1], aN, 0, 0, 0);
            aR = MFMA(alo1, whi[0][1], aR, 0, 0, 0);
            aZ = MFMA(alo1, whi[1][1], aZ, 0, 0, 0);
            aN = MFMA(alo1, whi[2][1], aN, 0, 0, 0);
            aR = MFMA(ahi1, wlo[0][1], aR, 0, 0, 0);
            aZ = MFMA(ahi1, wlo[1][1], aZ, 0, 0, 0);
            aN = MFMA(ahi1, wlo[2][1], aN, 0, 0, 0);

#pragma unroll
            for (int r = 0; r < 4; ++r) {
                float eR = __builtin_amdgcn_exp2f(__builtin_fmaf(-L2E, aR[r], cR));
                float rg = __builtin_amdgcn_rcpf(eR + 1.0f);
                float eZ = __builtin_amdgcn_exp2f(__builtin_fmaf(-L2E, aZ[r], cZ));
                float zg = __builtin_amdgcn_rcpf(eZ + 1.0f);
                float m  = aN[r] + bnacc;
                float eN = __builtin_amdgcn_exp2f(__builtin_fmaf(2.0f * L2E, rg * m, cN));
                float d  = __builtin_amdgcn_rcpf(eN + 1.0f);
                float ng = __builtin_fmaf(-2.0f, d, 1.0f);
                float hn = __builtin_fmaf(zg, hprev[r] - ng, ng);
                hprev[r] = hn;
                __bf16 hb = (__bf16)hn;
                Nh[wroff + r * SB] = hb;
                Nl[wroff + r * SB] = (__bf16)(hn - (float)hb);
            }
            __syncthreads();   // state i+1 published
        }
        oph += 8;   // 4 steps x 2 output cols
    }

    // final output: row 179 (state 180, in buf 0), duty wave 3
    if (w == 3) {
        const __bf16* Hh = hbuf[0][0];
        const __bf16* Hl = hbuf[0][1];
        bf16x8 ahi0 = *(const bf16x8*)(Hh + rdoff);
        bf16x8 ahi1 = *(const bf16x8*)(Hh + rdoff + 32);
        bf16x8 alo0 = *(const bf16x8*)(Hl + rdoff);
        bf16x8 alo1 = *(const bf16x8*)(Hl + rdoff + 32);
        f32x4 o = obias;
        o = MFMA(ahi0, obhi[0], o, 0, 0, 0);
        o = MFMA(ahi1, obhi[1], o, 0, 0, 0);
        o = MFMA(alo0, obhi[0], o, 0, 0, 0);
        o = MFMA(alo1, obhi[1], o, 0, 0, 0);
        o = MFMA(ahi0, oblo[0], o, 0, 0, 0);
        o = MFMA(ahi1, oblo[1], o, 0, 0, 0);
        if (n16 < 2) {
#pragma unroll
            for (int r = 0; r < 4; ++r)
                oph[r * (SEQ * 2) - 2] = o[r];
        }
    }
}

extern "C" void kernel_launch(void* const* d_in, const int* in_sizes, int n_in,
                              void* d_out, int out_size, void* d_ws, size_t ws_size,
                              hipStream_t stream) {
    (void)in_sizes; (void)n_in; (void)out_size; (void)d_ws; (void)ws_size;
    const float* z       = (const float*)d_in[0];
    const int*   labels  = (const int*)d_in[1];
    const float* embed_w = (const float*)d_in[2];
    const float* fc_w    = (const float*)d_in[3];
    const float* fc_b    = (const float*)d_in[4];
    // d_in[5] = w_ih: unused (GRU input is all zeros; b_ih carries the effect)
    const float* w_hh    = (const float*)d_in[6];
    const float* b_ih    = (const float*)d_in[7];
    const float* b_hh    = (const float*)d_in[8];
    const float* out_w   = (const float*)d_in[9];
    const float* out_b   = (const float*)d_in[10];
    float* out = (float*)d_out;

    gru_all<<<NB / MT, 256, 0, stream>>>(z, labels, embed_w, fc_w, fc_b,
                                         w_hh, b_ih, b_hh, out_w, out_b, out);
}